// Round 6
// baseline (142.034 us; speedup 1.0000x reference)
//
#include <hip/hip_runtime.h>

// CompositeLoss R17: persistent 4-group software-pipelined loss_main.
// R16 post-mortem: d-pair amortization was cancelled by the occupancy it
// cost (8 vs 12 waves/CU) -- per-wave load exposure unchanged. R14-R16
// consistent picture: VALU floor ~12us, HBM floor ~18us, measured ~40us;
// the gap is serialized load-latency exposure once per group. R17 hides it
// INSIDE the thread: 4 groups/thread (fully unrolled, A/B reg buffers),
// loads of group i+1 pinned in flight while group i computes (~500cy VALU
// covers L2/HBM latency). Groups are base + i*2^18 -> same w4/h/d-low, so
// per-iteration addresses are base + compile-time constants; wv/hv are
// iteration-invariant, dv/od alternate even/odd (precomputed). Epilogue
// amortized 4x. Straight-line, no loop-carried dynamic indexing (the R12
// spill shape). __launch_bounds__(256,2): 256-VGPR budget for ~205 live.
// Tripwire: WRITE_SIZE ~0.26MB; >>1MB means spill -> revert.
// Partial rows: 4 waves/block * 1024 blocks = 4096 rows of 16.
//  0:M 1:Mx(d) 2:My(h) 3:Mz(w)  4:Smae 5:Smse 6:Sbg
//  7:Sgx 8:Sgy 9:Sgz  10:Stx 11:Sty 12:Stz
#define NACC 13
#define NPAD 16
#define NBLOCKS 1024   // 2^18 base threads; each does 4 groups
#define NROWS 4096     // NBLOCKS * 4 waves
#define NMID 16        // 4096 / 256

__device__ __forceinline__ float4 ld4(const float* p) {
    return *reinterpret_cast<const float4*>(p);
}

struct Regs {   // one group's 21 float4 loads
    float4 m0, mh, md;
    float4 P0[3], T0[3], PH[3], TH[3], PD[3], TD[3];
};

__device__ __forceinline__ void issue_loads(
    const float* __restrict__ pred, const float* __restrict__ target,
    const float* __restrict__ mask, int mb, int pb0, int oh, int od, Regs& r)
{
    r.m0 = ld4(mask + mb);
    r.mh = ld4(mask + mb + oh);
    r.md = ld4(mask + mb + od);
#pragma unroll
    for (int c = 0; c < 3; ++c) {
        const int pb = pb0 + c * 2097152;
        r.P0[c] = ld4(pred + pb);       r.T0[c] = ld4(target + pb);
        r.PD[c] = ld4(pred + pb + od);  r.TD[c] = ld4(target + pb + od);
        r.PH[c] = ld4(pred + pb + oh);  r.TH[c] = ld4(target + pb + oh);
    }
}

__device__ __forceinline__ void consume(
    const Regs& r, float wv, float hv, float dv, float* acc)
{
    const float4 m0 = r.m0, mh = r.mh, md = r.md;
    const float m4w = __shfl_down(m0.x, 1, 64);  // lane w4=31: garbage, wv=0

    const float mz0 = fminf(m0.x, m0.y), mz1 = fminf(m0.y, m0.z),
                mz2 = fminf(m0.z, m0.w), mz3 = fminf(m0.w, m4w) * wv;
    const float my0 = fminf(m0.x, mh.x) * hv, my1 = fminf(m0.y, mh.y) * hv,
                my2 = fminf(m0.z, mh.z) * hv, my3 = fminf(m0.w, mh.w) * hv;
    const float mx0 = fminf(m0.x, md.x) * dv, mx1 = fminf(m0.y, md.y) * dv,
                mx2 = fminf(m0.z, md.z) * dv, mx3 = fminf(m0.w, md.w) * dv;

    acc[0] += m0.x + m0.y + m0.z + m0.w;
    acc[1] += mx0 + mx1 + mx2 + mx3;
    acc[2] += my0 + my1 + my2 + my3;
    acc[3] += mz0 + mz1 + mz2 + mz3;

#pragma unroll
    for (int c = 0; c < 3; ++c) {
        const float4 p0 = r.P0[c], t0 = r.T0[c];
        const float4 ph = r.PH[c], th = r.TH[c];
        const float4 pd = r.PD[c], td = r.TD[c];
        const float  p4 = __shfl_down(p0.x, 1, 64);
        const float  t4 = __shfl_down(t0.x, 1, 64);

        const float e0x = p0.x - t0.x, e0y = p0.y - t0.y,
                    e0z = p0.z - t0.z, e0w = p0.w - t0.w;
        const float e4  = p4 - t4;

        acc[4] += fabsf(e0x)*m0.x + fabsf(e0y)*m0.y
                + fabsf(e0z)*m0.z + fabsf(e0w)*m0.w;
        acc[5] += e0x*e0x*m0.x + e0y*e0y*m0.y
                + e0z*e0z*m0.z + e0w*e0w*m0.w;
        acc[6] += fabsf(p0.x)*(1.f-m0.x) + fabsf(p0.y)*(1.f-m0.y)
                + fabsf(p0.z)*(1.f-m0.z) + fabsf(p0.w)*(1.f-m0.w);

        // W direction (reference dz); mz3=0 at w-boundary kills shfl garbage
        acc[9]  += fabsf(e0y-e0x)*mz0 + fabsf(e0z-e0y)*mz1
                 + fabsf(e0w-e0z)*mz2 + fabsf(e4 -e0w)*mz3;
        acc[12] += fabsf(p0.y-p0.x)*mz0 + fabsf(p0.z-p0.y)*mz1
                 + fabsf(p0.w-p0.z)*mz2 + fabsf(p4  -p0.w)*mz3;

        // H direction (reference dy); my*=0 at h-boundary
        acc[8]  += fabsf((ph.x-th.x)-e0x)*my0 + fabsf((ph.y-th.y)-e0y)*my1
                 + fabsf((ph.z-th.z)-e0z)*my2 + fabsf((ph.w-th.w)-e0w)*my3;
        acc[11] += fabsf(ph.x-p0.x)*my0 + fabsf(ph.y-p0.y)*my1
                 + fabsf(ph.z-p0.z)*my2 + fabsf(ph.w-p0.w)*my3;

        // D direction (reference dx); mx*=0 at d-boundary
        acc[7]  += fabsf((pd.x-td.x)-e0x)*mx0 + fabsf((pd.y-td.y)-e0y)*mx1
                 + fabsf((pd.z-td.z)-e0z)*mx2 + fabsf((pd.w-td.w)-e0w)*mx3;
        acc[10] += fabsf(pd.x-p0.x)*mx0 + fabsf(pd.y-p0.y)*mx1
                 + fabsf(pd.z-p0.z)*mx2 + fabsf(pd.w-p0.w)*mx3;
    }
}

__global__ __launch_bounds__(256, 2) void loss_main(
    const float* __restrict__ pred, const float* __restrict__ target,
    const float* __restrict__ mask, float* __restrict__ partials)
{
    float acc[NACC];
#pragma unroll
    for (int k = 0; k < NACC; ++k) acc[k] = 0.f;

    // base covers bits 0..17 of the 20-bit group id: (d_low6, h, w4).
    // Iteration i adds bit18 (d_high) and bit19 (b):
    //   d = dlow + 64*(i&1), b = i>>1  ->  address = base + constant.
    const int base = blockIdx.x * 256 + threadIdx.x;
    const int w4   = base & 31;
    const int h    = (base >> 5) & 127;
    const int dlow = (base >> 12) & 63;
    const int w    = w4 << 2;

    const float wv = (w4 < 31) ? 1.f : 0.f;
    const float hv = (h < 127) ? 1.f : 0.f;
    const int   oh = (h < 127) ? 128 : 0;
    // even iterations: d = dlow <= 63 -> always interior in d
    const float dv_e = 1.f;
    const int   od_e = 16384;
    // odd iterations: d = 64 + dlow -> boundary iff dlow == 63
    const float dv_o = (dlow < 63) ? 1.f : 0.f;
    const int   od_o = (dlow < 63) ? 16384 : 0;

    const int mb00 = dlow * 16384 + h * 128 + w;   // b=0, d=dlow
    // mask strides: +1048576 per d_high, +2097152 per b
    // pred/target strides: +1048576 per d_high, +6291456 per b
    const int mb0 = mb00,            pb0 = mb00;               // i=0
    const int mb1 = mb00 + 1048576,  pb1 = mb00 + 1048576;     // i=1
    const int mb2 = mb00 + 2097152,  pb2 = mb00 + 6291456;     // i=2
    const int mb3 = mb00 + 3145728,  pb3 = mb00 + 7340032;     // i=3

    Regs A, B;
    // pipeline: L0 L1 C0 L2 C1 L3 C2 C3, pinned so loads stay ahead.
    issue_loads(pred, target, mask, mb0, pb0, oh, od_e, A);
    __builtin_amdgcn_sched_barrier(0);
    issue_loads(pred, target, mask, mb1, pb1, oh, od_o, B);
    __builtin_amdgcn_sched_barrier(0);
    consume(A, wv, hv, dv_e, acc);      // waits A only; B stays in flight
    __builtin_amdgcn_sched_barrier(0);
    issue_loads(pred, target, mask, mb2, pb2, oh, od_e, A);
    __builtin_amdgcn_sched_barrier(0);
    consume(B, wv, hv, dv_o, acc);
    __builtin_amdgcn_sched_barrier(0);
    issue_loads(pred, target, mask, mb3, pb3, oh, od_o, B);
    __builtin_amdgcn_sched_barrier(0);
    consume(A, wv, hv, dv_e, acc);
    __builtin_amdgcn_sched_barrier(0);
    consume(B, wv, hv, dv_o, acc);

    // per-wave shuffle reduce -> own partials row; NO __syncthreads.
    const int lane = threadIdx.x & 63;
    const int wave = threadIdx.x >> 6;
    float mine = 0.f;   // lane k (<16) ends up holding total of acc[k]
#pragma unroll
    for (int k = 0; k < NACC; ++k) {
        float v = acc[k];
        for (int o = 32; o > 0; o >>= 1) v += __shfl_down(v, o, 64);
        const float tot = __shfl(v, 0, 64);
        if (lane == k) mine = tot;
    }
    if (lane < NPAD)
        partials[(blockIdx.x * 4 + wave) * NPAD + lane] = mine; // pad rows=0
}

// Level 1: 16 blocks x 256 threads; thread r reads row r (4 independent
// float4), block-reduces 256 rows -> 1 row. 16 CUs share the 256 KiB read.
__global__ __launch_bounds__(256) void loss_mid(
    const float* __restrict__ partials, float* __restrict__ mid)
{
    const int r = blockIdx.x * 256 + threadIdx.x;   // exactly covers 4096
    const float* row = partials + r * NPAD;
    const float4 r0 = ld4(row);     const float4 r1 = ld4(row + 4);
    const float4 r2 = ld4(row + 8); const float4 r3 = ld4(row + 12);
    float acc[NPAD] = {r0.x, r0.y, r0.z, r0.w, r1.x, r1.y, r1.z, r1.w,
                       r2.x, r2.y, r2.z, r2.w, r3.x, r3.y, r3.z, r3.w};

    const int lane = threadIdx.x & 63;
    const int wave = threadIdx.x >> 6;
    __shared__ float red[4][NPAD];
#pragma unroll
    for (int k = 0; k < NPAD; ++k) {
        float v = acc[k];
        for (int o = 32; o > 0; o >>= 1) v += __shfl_down(v, o, 64);
        if (lane == 0) red[wave][k] = v;
    }
    __syncthreads();
    if (threadIdx.x < NPAD) {
        const int k = threadIdx.x;
        mid[blockIdx.x * NPAD + k] =
            red[0][k] + red[1][k] + red[2][k] + red[3][k];
    }
}

// Level 2: one wave; lane l (<16) reads mid row l, shuffle-reduce,
// lane 0 does the scalar epilogue.
__global__ __launch_bounds__(64) void loss_final(
    const float* __restrict__ mid, float* __restrict__ out)
{
    const int lane = threadIdx.x;
    float acc[NPAD];
    if (lane < NMID) {
        const float* row = mid + lane * NPAD;
        const float4 r0 = ld4(row);     const float4 r1 = ld4(row + 4);
        const float4 r2 = ld4(row + 8); const float4 r3 = ld4(row + 12);
        acc[0] = r0.x;  acc[1] = r0.y;  acc[2] = r0.z;  acc[3] = r0.w;
        acc[4] = r1.x;  acc[5] = r1.y;  acc[6] = r1.z;  acc[7] = r1.w;
        acc[8] = r2.x;  acc[9] = r2.y;  acc[10] = r2.z; acc[11] = r2.w;
        acc[12] = r3.x; acc[13] = r3.y; acc[14] = r3.z; acc[15] = r3.w;
    } else {
#pragma unroll
        for (int k = 0; k < NPAD; ++k) acc[k] = 0.f;
    }
#pragma unroll
    for (int k = 0; k < NACC; ++k) {
        for (int o = 32; o > 0; o >>= 1) acc[k] += __shfl_down(acc[k], o, 64);
    }
    if (lane == 0) {
        const float EPS = 1e-8f;
        const float M = acc[0], Mx = acc[1], My = acc[2], Mz = acc[3];
        float loss = (acc[4] + acc[5]) / (3.f * M + EPS);   // W_MAE=1, W_MSE=1
        loss += 0.1f   * (acc[7] / (3.f*Mx + EPS) + acc[8] / (3.f*My + EPS)
                        + acc[9] / (3.f*Mz + EPS));
        loss += 0.002f * (acc[10] / (3.f*Mx + EPS) + acc[11] / (3.f*My + EPS)
                        + acc[12] / (3.f*Mz + EPS));
        const float inv = 4194304.f - M;  // B*D*H*W - M
        loss += 0.15f * acc[6] / (3.f * inv + EPS);
        out[0] = loss;
    }
}

extern "C" void kernel_launch(void* const* d_in, const int* in_sizes, int n_in,
                              void* d_out, int out_size, void* d_ws, size_t ws_size,
                              hipStream_t stream) {
    const float* pred   = (const float*)d_in[0];
    const float* target = (const float*)d_in[1];
    const float* mask   = (const float*)d_in[2];
    float* out      = (float*)d_out;
    float* partials = (float*)d_ws;                 // 4096*16 floats = 256 KiB
    float* mid      = partials + NROWS * NPAD;      // 16*16 floats

    loss_main<<<NBLOCKS, 256, 0, stream>>>(pred, target, mask, partials);
    loss_mid<<<NMID, 256, 0, stream>>>(partials, mid);
    loss_final<<<1, 64, 0, stream>>>(mid, out);
}